// Round 4
// baseline (1643.772 us; speedup 1.0000x reference)
//
#include <hip/hip_runtime.h>

#define NN 50000
#define EE 400000
#define DD 64

typedef __bf16 bf16x8 __attribute__((ext_vector_type(8)));
typedef float f32x4 __attribute__((ext_vector_type(4)));

static __device__ __forceinline__ ushort f2bf(float f) {
    union { float f; unsigned int i; } x; x.f = f;
    unsigned int r = x.i + 0x7fffu + ((x.i >> 16) & 1u);
    return (ushort)(r >> 16);
}
static __device__ __forceinline__ float bf2f(ushort u) {
    union { unsigned int i; float f; } x; x.i = ((unsigned int)u) << 16; return x.f;
}

// ---------------- prep: swizzle f32 weights into bf16 MFMA B-fragment order ----------------
// B1P[((kc*4+quad)*64 + n)*8 + j] = bf16(W1[k][n]), k = kc*32+quad*8+j (zero-pad k>=144)
__global__ __launch_bounds__(256) void prep_edge_k(
    const float* __restrict__ W1, const float* __restrict__ W2,
    const float* __restrict__ b1, const float* __restrict__ b2,
    ushort* __restrict__ B1P, ushort* __restrict__ B2P,
    float* __restrict__ b1f, float* __restrict__ b2f)
{
    int idx = blockIdx.x * 256 + threadIdx.x;
    if (idx < 10240) {
        int j = idx & 7, n = (idx >> 3) & 63, qk = idx >> 9;
        int kc = qk >> 2, quad = qk & 3;
        int k = kc * 32 + quad * 8 + j;
        B1P[idx] = (k < 144) ? f2bf(W1[k * 64 + n]) : (ushort)0;
    }
    if (idx < 4096) {
        int j = idx & 7, n = (idx >> 3) & 63, qk = idx >> 9;
        int kc = qk >> 2, quad = qk & 3;
        int k = kc * 32 + quad * 8 + j;
        B2P[idx] = f2bf(W2[k * 64 + n]);
    }
    if (idx < 64) { b1f[idx] = b1[idx]; b2f[idx] = b2[idx]; }
}

// Wd1T [64][132] f32 (transposed, padded); Wd2T [64][68]
__global__ __launch_bounds__(256) void prep_node_k(
    const float* __restrict__ Wd1, const float* __restrict__ Wd2,
    const float* __restrict__ bd1, const float* __restrict__ lng,
    const float* __restrict__ lnb, const float* __restrict__ bd2,
    float* __restrict__ Wd1T, float* __restrict__ Wd2T,
    float* __restrict__ bd1f, float* __restrict__ lngf,
    float* __restrict__ lnbf, float* __restrict__ bd2f)
{
    int idx = blockIdx.x * 256 + threadIdx.x;
    if (idx < 64 * 132) {
        int j = idx / 132, k = idx - j * 132;
        Wd1T[idx] = (k < 128) ? Wd1[k * 64 + j] : 0.f;
    }
    if (idx < 64 * 68) {
        int j = idx / 68, k = idx - j * 68;
        Wd2T[idx] = (k < 64) ? Wd2[k * 64 + j] : 0.f;
    }
    if (idx < 64) {
        bd1f[idx] = bd1[idx]; lngf[idx] = lng[idx];
        lnbf[idx] = lnb[idx]; bd2f[idx] = bd2[idx];
    }
}

// ---------------- state: h = (t==0 ? 2*hseq : h + hseq); bf16 mirror ----------------
__global__ __launch_bounds__(256) void state_k(
    float* __restrict__ h, ushort* __restrict__ hb,
    const float* __restrict__ hseq_t, int mode)
{
    int i = blockIdx.x * 256 + threadIdx.x;   // exactly N*64 threads
    float v = hseq_t[i];
    float r = (mode == 0) ? (2.f * v) : (h[i] + v);
    h[i] = r; hb[i] = f2bf(r);
}

// ---------------- edge_attr f32 -> bf16 (per t, reused by both Euler steps) ----------------
__global__ __launch_bounds__(256) void eacvt_k(const float* __restrict__ ea, ushort* __restrict__ eab) {
    int i = blockIdx.x * 256 + threadIdx.x;   // exactly E*16 threads
    eab[i] = f2bf(ea[i]);
}

// ---------------- CSR build ----------------
__global__ __launch_bounds__(256) void zero_k(int* __restrict__ p, int n) {
    int i = blockIdx.x * 256 + threadIdx.x;
    if (i < n) p[i] = 0;
}
__global__ __launch_bounds__(256) void zero_f(float* __restrict__ p) {
    int i = blockIdx.x * 256 + threadIdx.x;   // exactly NN*64
    p[i] = 0.f;
}
__global__ __launch_bounds__(256) void hist_k(const int* __restrict__ rows, int* __restrict__ counts) {
    int e = blockIdx.x * 256 + threadIdx.x;
    if (e < EE) atomicAdd(&counts[rows[e]], 1);
}
__global__ __launch_bounds__(1024) void scan_k(
    const int* __restrict__ counts, int* __restrict__ offsets, int* __restrict__ cursor, int n)
{
    __shared__ int wsum[16];
    __shared__ int carry_s;
    int tid = threadIdx.x, lane = tid & 63, w = tid >> 6;
    if (tid == 0) carry_s = 0;
    __syncthreads();
    for (int base = 0; base < n; base += 1024) {
        int i = base + tid;
        int v = (i < n) ? counts[i] : 0;
        int x = v;
        for (int off = 1; off < 64; off <<= 1) {
            int y = __shfl_up(x, off);
            if (lane >= off) x += y;
        }
        if (lane == 63) wsum[w] = x;
        __syncthreads();
        if (w == 0 && lane < 16) {
            int s = wsum[lane];
            for (int off = 1; off < 16; off <<= 1) {
                int y = __shfl_up(s, off);
                if (lane >= off) s += y;
            }
            wsum[lane] = s;
        }
        __syncthreads();
        int wpre = (w == 0) ? 0 : wsum[w - 1];
        int excl = carry_s + wpre + x - v;
        if (i < n) { offsets[i] = excl; cursor[i] = excl; }
        int total = wsum[15];
        __syncthreads();
        if (tid == 0) carry_s += total;
        __syncthreads();
    }
    if (tid == 0) offsets[n] = carry_s;
}
__global__ __launch_bounds__(256) void fill_k(
    const int* __restrict__ rows, int* __restrict__ cursor, int* __restrict__ eslot)
{
    int e = blockIdx.x * 256 + threadIdx.x;
    if (e < EE) {
        int p = atomicAdd(&cursor[rows[e]], 1);
        if ((unsigned)p < (unsigned)EE) eslot[p] = e;
    }
}

// ---------------- edge MLP: msg = relu([h_r||h_c||ea]@W1+b1)@W2+b2 ----------------
// ATOMIC=0: store msg[E][64] bf16.  ATOMIC=1: atomicAdd into agg[N][64] f32.
template<int ATOMIC>
__global__ __launch_bounds__(256) void edge_k(
    const ushort* __restrict__ hb, const ushort* __restrict__ eab,
    const int* __restrict__ rows, const int* __restrict__ cols,
    const ushort* __restrict__ B1P, const ushort* __restrict__ B2P,
    const float* __restrict__ b1f, const float* __restrict__ b2f,
    ushort* __restrict__ msg, float* __restrict__ agg)
{
    __shared__ __attribute__((aligned(16))) ushort sB1[10240];
    __shared__ __attribute__((aligned(16))) ushort sB2[4096];
    __shared__ __attribute__((aligned(16))) ushort sA[64 * 168];  // 160 used, pad->168
    __shared__ __attribute__((aligned(16))) ushort sH[64 * 72];   // hidden, pad 64->72
    __shared__ int sRow[64], sCol[64];

    int tid = threadIdx.x;
    int ebase = blockIdx.x * 64;

    for (int i = tid; i < 10240 / 8; i += 256) ((uint4*)sB1)[i] = ((const uint4*)B1P)[i];
    for (int i = tid; i < 4096 / 8; i += 256) ((uint4*)sB2)[i] = ((const uint4*)B2P)[i];
    if (tid < 64) sRow[tid] = rows[ebase + tid];
    else if (tid < 128) sCol[tid - 64] = cols[ebase + tid - 64];
    __syncthreads();

    // gather A-tile: 64 edges x 20 chunks(16B): [h_row(8)|h_col(8)|ea(2)|zero(2)]
    for (int c = tid; c < 1280; c += 256) {
        int el = c / 20;
        int p = c - el * 20;
        uint4 v;
        if (p < 8)       v = *(const uint4*)(hb + (size_t)sRow[el] * 64 + p * 8);
        else if (p < 16) v = *(const uint4*)(hb + (size_t)sCol[el] * 64 + (p - 8) * 8);
        else if (p < 18) v = *(const uint4*)(eab + (size_t)(ebase + el) * 16 + (p - 16) * 8);
        else             v = make_uint4(0u, 0u, 0u, 0u);
        *(uint4*)(sA + el * 168 + p * 8) = v;
    }
    __syncthreads();

    int lane = tid & 63, wave = tid >> 6;
    int m = lane & 15, quad = lane >> 4;

    // layer 1: [16 edges x 160] @ [160 x 64]
    f32x4 acc[4];
    for (int nt = 0; nt < 4; nt++) acc[nt] = (f32x4){0.f, 0.f, 0.f, 0.f};
    for (int kc = 0; kc < 5; kc++) {
        bf16x8 a = *(const bf16x8*)(sA + (wave * 16 + m) * 168 + kc * 32 + quad * 8);
        for (int nt = 0; nt < 4; nt++) {
            bf16x8 b = *(const bf16x8*)(sB1 + ((kc * 4 + quad) * 64 + nt * 16 + m) * 8);
            acc[nt] = __builtin_amdgcn_mfma_f32_16x16x32_bf16(a, b, acc[nt], 0, 0, 0);
        }
    }
    // relu + b1 -> sH (bf16): C-layout row=quad*4+r, col=nt*16+m
    for (int nt = 0; nt < 4; nt++) {
        int colid = nt * 16 + m;
        float bb = b1f[colid];
        for (int r = 0; r < 4; r++) {
            float v = acc[nt][r] + bb;
            v = v > 0.f ? v : 0.f;
            sH[(wave * 16 + quad * 4 + r) * 72 + colid] = f2bf(v);
        }
    }
    __syncthreads();   // LDS handoff ordering (compiler + HW)
    // layer 2: [16 x 64] @ [64 x 64]
    f32x4 acc2[4];
    for (int nt = 0; nt < 4; nt++) acc2[nt] = (f32x4){0.f, 0.f, 0.f, 0.f};
    for (int kc = 0; kc < 2; kc++) {
        bf16x8 a = *(const bf16x8*)(sH + (wave * 16 + m) * 72 + kc * 32 + quad * 8);
        for (int nt = 0; nt < 4; nt++) {
            bf16x8 b = *(const bf16x8*)(sB2 + ((kc * 4 + quad) * 64 + nt * 16 + m) * 8);
            acc2[nt] = __builtin_amdgcn_mfma_f32_16x16x32_bf16(a, b, acc2[nt], 0, 0, 0);
        }
    }
    for (int nt = 0; nt < 4; nt++) {
        int colid = nt * 16 + m;
        float bb = b2f[colid];
        for (int r = 0; r < 4; r++) {
            float v = acc2[nt][r] + bb;
            int el = wave * 16 + quad * 4 + r;
            if (ATOMIC) {
                atomicAdd(&agg[(size_t)sRow[el] * 64 + colid], v);
            } else {
                msg[(size_t)(ebase + el) * 64 + colid] = f2bf(v);
            }
        }
    }
}

// ---------------- aggregate (CSR path): one wave per node, lane = feature ----------------
__global__ __launch_bounds__(256) void agg_k(
    const ushort* __restrict__ msg, const int* __restrict__ offsets,
    const int* __restrict__ eslot, float* __restrict__ agg)
{
    int gw = (blockIdx.x * 256 + threadIdx.x) >> 6;
    int lane = threadIdx.x & 63;
    int beg = offsets[gw], end = offsets[gw + 1];
    beg = beg < 0 ? 0 : beg;
    end = end > EE ? EE : end;
    float a = 0.f;
    for (int i = beg; i < end; i++) {
        int e = eslot[i];
        if ((unsigned)e < (unsigned)EE)
            a += bf2f(msg[(size_t)e * 64 + lane]);
    }
    agg[(size_t)gw * 64 + lane] = a;
}

// ---------------- node MLP + LN + SiLU + tanh + Euler update ----------------
__global__ __launch_bounds__(256) void node_k(
    float* __restrict__ h, ushort* __restrict__ hbm,
    const float* __restrict__ agg,
    const float* __restrict__ Wd1T, const float* __restrict__ Wd2T,
    const float* __restrict__ bd1f, const float* __restrict__ lngf,
    const float* __restrict__ lnbf, const float* __restrict__ bd2f)
{
    __shared__ __attribute__((aligned(16))) float sW1[64 * 132];
    __shared__ __attribute__((aligned(16))) float sW2[64 * 68];
    __shared__ __attribute__((aligned(16))) float sV[4][4][128];
    __shared__ __attribute__((aligned(16))) float sX[4][4][64];
    int tid = threadIdx.x;
    for (int i = tid; i < 64 * 132 / 4; i += 256) ((float4*)sW1)[i] = ((const float4*)Wd1T)[i];
    for (int i = tid; i < 64 * 68 / 4; i += 256) ((float4*)sW2)[i] = ((const float4*)Wd2T)[i];

    int lane = tid & 63, wave = tid >> 6;
    int nbase = blockIdx.x * 16 + wave * 4;

    for (int i = lane; i < 512; i += 64) {
        int v = i >> 7, k = i & 127;
        int n = nbase + v;
        sV[wave][v][k] = (k < 64) ? h[(size_t)n * 64 + k] : agg[(size_t)n * 64 + (k - 64)];
    }
    __syncthreads();

    float acc[4] = {0.f, 0.f, 0.f, 0.f};
    for (int k = 0; k < 128; k += 4) {
        float4 wv = *(const float4*)&sW1[lane * 132 + k];
        for (int v = 0; v < 4; v++) {
            float4 xv = *(const float4*)&sV[wave][v][k];
            acc[v] += wv.x * xv.x + wv.y * xv.y + wv.z * xv.z + wv.w * xv.w;
        }
    }
    float bd1v = bd1f[lane], gg = lngf[lane], bb = lnbf[lane], bd2v = bd2f[lane];
    for (int v = 0; v < 4; v++) {
        float x = acc[v] + bd1v;
        float s1 = x, s2 = x * x;
        for (int off = 1; off < 64; off <<= 1) {
            s1 += __shfl_xor(s1, off);
            s2 += __shfl_xor(s2, off);
        }
        float mean = s1 * (1.f / 64.f);
        float var = s2 * (1.f / 64.f) - mean * mean;
        var = fmaxf(var, 0.f);
        float xn = (x - mean) * rsqrtf(var + 1e-5f) * gg + bb;
        sX[wave][v][lane] = xn / (1.f + __expf(-xn));
    }
    __syncthreads();
    float acc2[4] = {0.f, 0.f, 0.f, 0.f};
    for (int k = 0; k < 64; k += 4) {
        float4 wv = *(const float4*)&sW2[lane * 68 + k];
        for (int v = 0; v < 4; v++) {
            float4 xv = *(const float4*)&sX[wave][v][k];
            acc2[v] += wv.x * xv.x + wv.y * xv.y + wv.z * xv.z + wv.w * xv.w;
        }
    }
    for (int v = 0; v < 4; v++) {
        int n = nbase + v;
        float y = tanhf(acc2[v] + bd2v);
        float hn = h[(size_t)n * 64 + lane] + 0.5f * y;
        h[(size_t)n * 64 + lane] = hn;
        hbm[(size_t)n * 64 + lane] = f2bf(hn);
    }
}

// ---------------- disagreement (f32 out) + final (f32 out) ----------------
__global__ __launch_bounds__(256) void dis_k(
    const float* __restrict__ h, const int* __restrict__ rows,
    const int* __restrict__ cols, float* __restrict__ outp)
{
    int tid = threadIdx.x;
    int e = blockIdx.x * 16 + (tid >> 4);
    int l16 = tid & 15;
    int r = rows[e], c = cols[e];
    float4 a = *(const float4*)(h + (size_t)r * 64 + l16 * 4);
    float4 b = *(const float4*)(h + (size_t)c * 64 + l16 * 4);
    float dx = a.x - b.x, dy = a.y - b.y, dz = a.z - b.z, dw = a.w - b.w;
    float s = dx * dx + dy * dy + dz * dz + dw * dw;
    for (int off = 1; off < 16; off <<= 1) s += __shfl_xor(s, off);
    if (l16 == 0) outp[e] = (s < 1e4f ? s : 1e4f);
}

__global__ __launch_bounds__(256) void final_k(const float* __restrict__ h, float* __restrict__ out) {
    int i = blockIdx.x * 256 + threadIdx.x;
    out[i] = h[i];
}

extern "C" void kernel_launch(void* const* d_in, const int* in_sizes, int n_in,
                              void* d_out, int out_size, void* d_ws, size_t ws_size,
                              hipStream_t stream) {
    const float* h_seq = (const float*)d_in[0];
    const float* eattr = (const float*)d_in[1];
    const float* W1 = (const float*)d_in[2];
    const float* b1 = (const float*)d_in[3];
    const float* W2 = (const float*)d_in[4];
    const float* b2 = (const float*)d_in[5];
    const float* Wd1 = (const float*)d_in[6];
    const float* bd1 = (const float*)d_in[7];
    const float* lng = (const float*)d_in[8];
    const float* lnb = (const float*)d_in[9];
    const float* Wd2 = (const float*)d_in[10];
    const float* bd2 = (const float*)d_in[11];
    const int* ei = (const int*)d_in[12];
    float* out = (float*)d_out;

    // Workspace: small/critical buffers first, big msg LAST (ws_size guard).
    char* wsp = (char*)d_ws;
    size_t used = 0;
    auto carve = [&](size_t b) {
        void* p = (void*)(wsp + used);
        used += (b + 255) & ~(size_t)255;
        return p;
    };
    int* counts   = (int*)carve((size_t)NN * 4);
    int* offsets  = (int*)carve((size_t)(NN + 1) * 4);
    int* cursor   = (int*)carve((size_t)NN * 4);
    int* eslot    = (int*)carve((size_t)EE * 4);
    ushort* B1P   = (ushort*)carve(10240 * 2);
    ushort* B2P   = (ushort*)carve(4096 * 2);
    float* Wd1T   = (float*)carve(64 * 132 * 4);
    float* Wd2T   = (float*)carve(64 * 68 * 4);
    float* b1f    = (float*)carve(256);
    float* b2f    = (float*)carve(256);
    float* bd1f   = (float*)carve(256);
    float* lngf   = (float*)carve(256);
    float* lnbf   = (float*)carve(256);
    float* bd2f   = (float*)carve(256);
    float* h      = (float*)carve((size_t)NN * 64 * 4);
    ushort* hb    = (ushort*)carve((size_t)NN * 64 * 2);
    float* agg    = (float*)carve((size_t)NN * 64 * 4);
    ushort* eab   = (ushort*)carve((size_t)EE * 16 * 2);
    ushort* msg   = (ushort*)carve((size_t)EE * 64 * 2);   // 51.2 MB — only if it fits
    const bool full = (used <= ws_size);   // deterministic -> graph-capture safe

    prep_edge_k<<<40, 256, 0, stream>>>(W1, W2, b1, b2, B1P, B2P, b1f, b2f);
    prep_node_k<<<33, 256, 0, stream>>>(Wd1, Wd2, bd1, lng, lnb, bd2, Wd1T, Wd2T, bd1f, lngf, lnbf, bd2f);

    for (int t = 0; t < 2; t++) {
        const int* rows = ei + (size_t)t * 2 * EE;
        const int* cols = rows + EE;
        state_k<<<12500, 256, 0, stream>>>(h, hb, h_seq + (size_t)t * NN * 64, t);
        eacvt_k<<<25000, 256, 0, stream>>>(eattr + (size_t)t * EE * 16, eab);
        if (full) {
            zero_k<<<196, 256, 0, stream>>>(counts, NN);
            hist_k<<<1563, 256, 0, stream>>>(rows, counts);
            scan_k<<<1, 1024, 0, stream>>>(counts, offsets, cursor, NN);
            fill_k<<<1563, 256, 0, stream>>>(rows, cursor, eslot);
        }
        for (int s = 0; s < 2; s++) {
            if (full) {
                edge_k<0><<<6250, 256, 0, stream>>>(hb, eab, rows, cols,
                                                    B1P, B2P, b1f, b2f, msg, agg);
                agg_k<<<12500, 256, 0, stream>>>(msg, offsets, eslot, agg);
            } else {
                zero_f<<<12500, 256, 0, stream>>>(agg);
                edge_k<1><<<6250, 256, 0, stream>>>(hb, eab, rows, cols,
                                                    B1P, B2P, b1f, b2f, msg, agg);
            }
            node_k<<<3125, 256, 0, stream>>>(h, hb, agg, Wd1T, Wd2T, bd1f, lngf, lnbf, bd2f);
        }
        dis_k<<<25000, 256, 0, stream>>>(h, rows, cols, out + (size_t)NN * 64 + (size_t)t * EE);
    }
    final_k<<<12500, 256, 0, stream>>>(h, out);
}

// Round 7
// 1130.919 us; speedup vs baseline: 1.4535x; 1.4535x over previous
//
#include <hip/hip_runtime.h>

#define NN 50000
#define EE 400000
#define DD 64
#define NTILE ((EE + 63) / 64)        // 6250 edge tiles
#define EGRID 1024                    // persistent edge blocks
#define NBLK ((NN + 63) / 64)         // 782 node blocks

typedef __bf16 bf16x8 __attribute__((ext_vector_type(8)));
typedef float f32x4 __attribute__((ext_vector_type(4)));

static __device__ __forceinline__ ushort f2bf(float f) {
    union { float f; unsigned int i; } x; x.f = f;
    unsigned int r = x.i + 0x7fffu + ((x.i >> 16) & 1u);
    return (ushort)(r >> 16);
}
static __device__ __forceinline__ float bf2f(ushort u) {
    union { unsigned int i; float f; } x; x.i = ((unsigned int)u) << 16; return x.f;
}
static __device__ __forceinline__ unsigned pack2(float lo, float hi) {
    return (unsigned)f2bf(lo) | ((unsigned)f2bf(hi) << 16);
}
static __device__ __forceinline__ float fast_tanh(float x) {
    float e = __expf(2.f * x);
    return 1.f - 2.f / (e + 1.f);
}

// ---------------- prep: swizzle f32 weights into bf16 MFMA B-fragment order ----------------
__global__ __launch_bounds__(256) void prep_edge_k(
    const float* __restrict__ W1, const float* __restrict__ W2,
    const float* __restrict__ b1, const float* __restrict__ b2,
    ushort* __restrict__ B1P, ushort* __restrict__ B2P,
    float* __restrict__ b1f, float* __restrict__ b2f)
{
    int idx = blockIdx.x * 256 + threadIdx.x;
    if (idx < 10240) {
        int j = idx & 7, n = (idx >> 3) & 63, qk = idx >> 9;
        int kc = qk >> 2, quad = qk & 3;
        int k = kc * 32 + quad * 8 + j;
        B1P[idx] = (k < 144) ? f2bf(W1[k * 64 + n]) : (ushort)0;
    }
    if (idx < 4096) {
        int j = idx & 7, n = (idx >> 3) & 63, qk = idx >> 9;
        int kc = qk >> 2, quad = qk & 3;
        int k = kc * 32 + quad * 8 + j;
        B2P[idx] = f2bf(W2[k * 64 + n]);
    }
    if (idx < 64) { b1f[idx] = b1[idx]; b2f[idx] = b2[idx]; }
}

// node weights: Wd1 [128x64] -> Wd1P frag image (8192), Wd2 [64x64] -> Wd2P (4096)
__global__ __launch_bounds__(256) void prep_node_k(
    const float* __restrict__ Wd1, const float* __restrict__ Wd2,
    const float* __restrict__ bd1, const float* __restrict__ lng,
    const float* __restrict__ lnb, const float* __restrict__ bd2,
    ushort* __restrict__ Wd1P, ushort* __restrict__ Wd2P,
    float* __restrict__ bd1f, float* __restrict__ lngf,
    float* __restrict__ lnbf, float* __restrict__ bd2f)
{
    int idx = blockIdx.x * 256 + threadIdx.x;
    if (idx < 8192) {
        int j = idx & 7, n = (idx >> 3) & 63, qk = idx >> 9;   // qk 0..15
        int kc = qk >> 2, quad = qk & 3;
        int k = kc * 32 + quad * 8 + j;                        // 0..127
        Wd1P[idx] = f2bf(Wd1[k * 64 + n]);
    }
    if (idx < 4096) {
        int j = idx & 7, n = (idx >> 3) & 63, qk = idx >> 9;   // qk 0..7
        int kc = qk >> 2, quad = qk & 3;
        int k = kc * 32 + quad * 8 + j;                        // 0..63
        Wd2P[idx] = f2bf(Wd2[k * 64 + n]);
    }
    if (idx < 64) {
        bd1f[idx] = bd1[idx]; lngf[idx] = lng[idx];
        lnbf[idx] = lnb[idx]; bd2f[idx] = bd2[idx];
    }
}

// ---------------- state: h = (t==0 ? 2*hseq : h + hseq); bf16 mirror ----------------
__global__ __launch_bounds__(256) void state_k(
    float* __restrict__ h, ushort* __restrict__ hb,
    const float* __restrict__ hseq_t, int mode)
{
    int i = blockIdx.x * 256 + threadIdx.x;
    float v = hseq_t[i];
    float r = (mode == 0) ? (2.f * v) : (h[i] + v);
    h[i] = r; hb[i] = f2bf(r);
}

// ---------------- CSR build ----------------
__global__ __launch_bounds__(256) void zero_k(int* __restrict__ p, int n) {
    int i = blockIdx.x * 256 + threadIdx.x;
    if (i < n) p[i] = 0;
}
__global__ __launch_bounds__(256) void zero_f(float* __restrict__ p) {
    int i = blockIdx.x * 256 + threadIdx.x;
    p[i] = 0.f;
}
__global__ __launch_bounds__(256) void hist_k(const int* __restrict__ rows, int* __restrict__ counts) {
    int e = blockIdx.x * 256 + threadIdx.x;
    if (e < EE) atomicAdd(&counts[rows[e]], 1);
}
__global__ __launch_bounds__(1024) void scan_k(
    const int* __restrict__ counts, int* __restrict__ offsets, int* __restrict__ cursor, int n)
{
    __shared__ int wsum[16];
    __shared__ int carry_s;
    int tid = threadIdx.x, lane = tid & 63, w = tid >> 6;
    if (tid == 0) carry_s = 0;
    __syncthreads();
    for (int base = 0; base < n; base += 1024) {
        int i = base + tid;
        int v = (i < n) ? counts[i] : 0;
        int x = v;
        for (int off = 1; off < 64; off <<= 1) {
            int y = __shfl_up(x, off);
            if (lane >= off) x += y;
        }
        if (lane == 63) wsum[w] = x;
        __syncthreads();
        if (w == 0 && lane < 16) {
            int s = wsum[lane];
            for (int off = 1; off < 16; off <<= 1) {
                int y = __shfl_up(s, off);
                if (lane >= off) s += y;
            }
            wsum[lane] = s;
        }
        __syncthreads();
        int wpre = (w == 0) ? 0 : wsum[w - 1];
        int excl = carry_s + wpre + x - v;
        if (i < n) { offsets[i] = excl; cursor[i] = excl; }
        int total = wsum[15];
        __syncthreads();
        if (tid == 0) carry_s += total;
        __syncthreads();
    }
    if (tid == 0) offsets[n] = carry_s;
}
__global__ __launch_bounds__(256) void fill_k(
    const int* __restrict__ rows, int* __restrict__ cursor, int* __restrict__ eslot)
{
    int e = blockIdx.x * 256 + threadIdx.x;
    if (e < EE) {
        int p = atomicAdd(&cursor[rows[e]], 1);
        if ((unsigned)p < (unsigned)EE) eslot[p] = e;
    }
}

// ---------------- edge MLP (persistent tiles): msg = relu([h_r||h_c||ea]@W1+b1)@W2+b2 ----------------
template<int ATOMIC>
__global__ __launch_bounds__(256) void edge_k(
    const ushort* __restrict__ hb, const float* __restrict__ ea,
    const int* __restrict__ rows, const int* __restrict__ cols,
    const ushort* __restrict__ B1P, const ushort* __restrict__ B2P,
    const float* __restrict__ b1f, const float* __restrict__ b2f,
    ushort* __restrict__ msg, float* __restrict__ agg)
{
    __shared__ __attribute__((aligned(16))) ushort sB1[10240];
    __shared__ __attribute__((aligned(16))) ushort sB2[4096];
    __shared__ __attribute__((aligned(16))) ushort sA[64 * 168];  // pad 160->168 (bank-safe)
    __shared__ __attribute__((aligned(16))) ushort sH[64 * 72];

    int tid = threadIdx.x;
    int lane = tid & 63, wave = tid >> 6;
    int m = lane & 15, quad = lane >> 4;

    // stage weights ONCE per persistent block
    for (int i = tid; i < 10240 / 8; i += 256) ((uint4*)sB1)[i] = ((const uint4*)B1P)[i];
    for (int i = tid; i < 4096 / 8; i += 256) ((uint4*)sB2)[i] = ((const uint4*)B2P)[i];

    for (int tile = blockIdx.x; tile < NTILE; tile += EGRID) {
        int ebase = tile * 64;
        __syncthreads();   // weights ready (1st iter) / sA+sH reuse guard (others)

        // gather: 64 edges x 20 chunks(16B): [h_row(8)|h_col(8)|ea f32->bf16(2)|zero(2)]
        for (int c = tid; c < 1280; c += 256) {
            int el = c / 20;
            int p = c - el * 20;
            uint4 v;
            if (p < 8) {
                int r = rows[ebase + el];
                v = *(const uint4*)(hb + (size_t)r * 64 + p * 8);
            } else if (p < 16) {
                int cc = cols[ebase + el];
                v = *(const uint4*)(hb + (size_t)cc * 64 + (p - 8) * 8);
            } else if (p < 18) {
                const float* s = ea + (size_t)(ebase + el) * 16 + (p - 16) * 8;
                float4 f0 = ((const float4*)s)[0], f1 = ((const float4*)s)[1];
                v = make_uint4(pack2(f0.x, f0.y), pack2(f0.z, f0.w),
                               pack2(f1.x, f1.y), pack2(f1.z, f1.w));
            } else {
                v = make_uint4(0u, 0u, 0u, 0u);
            }
            *(uint4*)(sA + el * 168 + p * 8) = v;
        }
        __syncthreads();

        // layer 1: [16 edges x 160] @ [160 x 64]
        f32x4 acc[4];
        for (int nt = 0; nt < 4; nt++) acc[nt] = (f32x4){0.f, 0.f, 0.f, 0.f};
        for (int kc = 0; kc < 5; kc++) {
            bf16x8 a = *(const bf16x8*)(sA + (wave * 16 + m) * 168 + kc * 32 + quad * 8);
            for (int nt = 0; nt < 4; nt++) {
                bf16x8 b = *(const bf16x8*)(sB1 + ((kc * 4 + quad) * 64 + nt * 16 + m) * 8);
                acc[nt] = __builtin_amdgcn_mfma_f32_16x16x32_bf16(a, b, acc[nt], 0, 0, 0);
            }
        }
        for (int nt = 0; nt < 4; nt++) {
            int colid = nt * 16 + m;
            float bb = b1f[colid];
            for (int r = 0; r < 4; r++) {
                float v = acc[nt][r] + bb;
                v = v > 0.f ? v : 0.f;
                sH[(wave * 16 + quad * 4 + r) * 72 + colid] = f2bf(v);
            }
        }
        __syncthreads();

        // layer 2: [16 x 64] @ [64 x 64]
        f32x4 acc2[4];
        for (int nt = 0; nt < 4; nt++) acc2[nt] = (f32x4){0.f, 0.f, 0.f, 0.f};
        for (int kc = 0; kc < 2; kc++) {
            bf16x8 a = *(const bf16x8*)(sH + (wave * 16 + m) * 72 + kc * 32 + quad * 8);
            for (int nt = 0; nt < 4; nt++) {
                bf16x8 b = *(const bf16x8*)(sB2 + ((kc * 4 + quad) * 64 + nt * 16 + m) * 8);
                acc2[nt] = __builtin_amdgcn_mfma_f32_16x16x32_bf16(a, b, acc2[nt], 0, 0, 0);
            }
        }
        for (int nt = 0; nt < 4; nt++) {
            int colid = nt * 16 + m;
            float bb = b2f[colid];
            for (int r = 0; r < 4; r++) {
                float v = acc2[nt][r] + bb;
                int el = wave * 16 + quad * 4 + r;
                if (ATOMIC) {
                    atomicAdd(&agg[(size_t)rows[ebase + el] * 64 + colid], v);
                } else {
                    msg[(size_t)(ebase + el) * 64 + colid] = f2bf(v);
                }
            }
        }
    }
}

// ---------------- aggregate (CSR path): one wave per node, lane = feature ----------------
__global__ __launch_bounds__(256) void agg_k(
    const ushort* __restrict__ msg, const int* __restrict__ offsets,
    const int* __restrict__ eslot, float* __restrict__ agg)
{
    int gw = (blockIdx.x * 256 + threadIdx.x) >> 6;
    int lane = threadIdx.x & 63;
    int beg = offsets[gw], end = offsets[gw + 1];
    beg = beg < 0 ? 0 : beg;
    end = end > EE ? EE : end;
    float a = 0.f;
    for (int i = beg; i < end; i++) {
        int e = eslot[i];
        if ((unsigned)e < (unsigned)EE)
            a += bf2f(msg[(size_t)e * 64 + lane]);
    }
    agg[(size_t)gw * 64 + lane] = a;
}

// ---------------- node MLP (MFMA) + in-register LN + SiLU + tanh + Euler ----------------
// 64 nodes per block; A = [64 x 128] bf16 (h||agg), B = prepped Wd1/Wd2 frag images.
__global__ __launch_bounds__(256) void node_k(
    float* __restrict__ h, ushort* __restrict__ hbm,
    const float* __restrict__ agg,
    const ushort* __restrict__ Wd1P, const ushort* __restrict__ Wd2P,
    const float* __restrict__ bd1f, const float* __restrict__ lngf,
    const float* __restrict__ lnbf, const float* __restrict__ bd2f)
{
    __shared__ __attribute__((aligned(16))) ushort sB1[8192];     // 16 KB
    __shared__ __attribute__((aligned(16))) ushort sB2[4096];     // 8 KB
    __shared__ __attribute__((aligned(16))) ushort sA[64 * 136];  // 17.4 KB, pad 128->136
    __shared__ __attribute__((aligned(16))) ushort sX[64 * 72];   // 9.2 KB
    int tid = threadIdx.x;
    int lane = tid & 63, wave = tid >> 6;
    int m = lane & 15, quad = lane >> 4;
    int nbase = blockIdx.x * 64;

    for (int i = tid; i < 8192 / 8; i += 256) ((uint4*)sB1)[i] = ((const uint4*)Wd1P)[i];
    for (int i = tid; i < 4096 / 8; i += 256) ((uint4*)sB2)[i] = ((const uint4*)Wd2P)[i];

    // gather A: 64 nodes x 16 chunks(8 bf16): [h f32->bf16 (8) | agg f32->bf16 (8)]
    for (int c = tid; c < 1024; c += 256) {
        int nd = c >> 4, p = c & 15;
        int n = nbase + nd; n = n < NN ? n : NN - 1;   // clamped rows are compute-only
        const float* src = (p < 8) ? (h + (size_t)n * 64 + p * 8)
                                   : (agg + (size_t)n * 64 + (p - 8) * 8);
        float4 f0 = ((const float4*)src)[0], f1 = ((const float4*)src)[1];
        *(uint4*)(sA + nd * 136 + p * 8) =
            make_uint4(pack2(f0.x, f0.y), pack2(f0.z, f0.w),
                       pack2(f1.x, f1.y), pack2(f1.z, f1.w));
    }
    __syncthreads();

    // layer 1: [16 nodes x 128] @ [128 x 64]
    f32x4 acc[4];
    for (int nt = 0; nt < 4; nt++) acc[nt] = (f32x4){0.f, 0.f, 0.f, 0.f};
    for (int kc = 0; kc < 4; kc++) {
        bf16x8 a = *(const bf16x8*)(sA + (wave * 16 + m) * 136 + kc * 32 + quad * 8);
        for (int nt = 0; nt < 4; nt++) {
            bf16x8 b = *(const bf16x8*)(sB1 + ((kc * 4 + quad) * 64 + nt * 16 + m) * 8);
            acc[nt] = __builtin_amdgcn_mfma_f32_16x16x32_bf16(a, b, acc[nt], 0, 0, 0);
        }
    }

    // LN in-register: lane holds node=quad*4+r, feature=nt*16+m (C-layout)
    float gA[4], bA[4], d1[4], d2[4];
    for (int nt = 0; nt < 4; nt++) {
        int f = nt * 16 + m;
        d1[nt] = bd1f[f]; gA[nt] = lngf[f]; bA[nt] = lnbf[f]; d2[nt] = bd2f[f];
    }
    float xs[4][4];
    for (int nt = 0; nt < 4; nt++)
        for (int r = 0; r < 4; r++)
            xs[nt][r] = acc[nt][r] + d1[nt];

    for (int r = 0; r < 4; r++) {
        float s1 = 0.f, s2 = 0.f;
        for (int nt = 0; nt < 4; nt++) { float v = xs[nt][r]; s1 += v; s2 += v * v; }
        for (int off = 1; off < 16; off <<= 1) {     // butterfly within 16-lane m-group
            s1 += __shfl_xor(s1, off);
            s2 += __shfl_xor(s2, off);
        }
        float mean = s1 * (1.f / 64.f);
        float var = fmaxf(s2 * (1.f / 64.f) - mean * mean, 0.f);
        float rstd = rsqrtf(var + 1e-5f);
        int nrow = wave * 16 + quad * 4 + r;
        for (int nt = 0; nt < 4; nt++) {
            float xn = (xs[nt][r] - mean) * rstd * gA[nt] + bA[nt];
            float sl = xn / (1.f + __expf(-xn));     // SiLU
            sX[nrow * 72 + nt * 16 + m] = f2bf(sl);
        }
    }
    __syncthreads();

    // layer 2: [16 x 64] @ [64 x 64]
    f32x4 acc2[4];
    for (int nt = 0; nt < 4; nt++) acc2[nt] = (f32x4){0.f, 0.f, 0.f, 0.f};
    for (int kc = 0; kc < 2; kc++) {
        bf16x8 a = *(const bf16x8*)(sX + (wave * 16 + m) * 72 + kc * 32 + quad * 8);
        for (int nt = 0; nt < 4; nt++) {
            bf16x8 b = *(const bf16x8*)(sB2 + ((kc * 4 + quad) * 64 + nt * 16 + m) * 8);
            acc2[nt] = __builtin_amdgcn_mfma_f32_16x16x32_bf16(a, b, acc2[nt], 0, 0, 0);
        }
    }

    // epilogue: tanh + Euler. RMW h — ONLY in-range slots write (tail slots are
    // duplicates of node NN-1; letting them write races the read-modify-write
    // and multiplies the Euler update — the R6 absmax=816 bug).
    for (int r = 0; r < 4; r++) {
        int g = nbase + wave * 16 + quad * 4 + r;
        if (g < NN) {
            for (int nt = 0; nt < 4; nt++) {
                int f = nt * 16 + m;
                float y = fast_tanh(acc2[nt][r] + d2[nt]);
                float hn = h[(size_t)g * 64 + f] + 0.5f * y;
                h[(size_t)g * 64 + f] = hn;
                hbm[(size_t)g * 64 + f] = f2bf(hn);
            }
        }
    }
}

// ---------------- disagreement (f32) + final (f32) ----------------
__global__ __launch_bounds__(256) void dis_k(
    const float* __restrict__ h, const int* __restrict__ rows,
    const int* __restrict__ cols, float* __restrict__ outp)
{
    int tid = threadIdx.x;
    int e = blockIdx.x * 16 + (tid >> 4);
    int l16 = tid & 15;
    int r = rows[e], c = cols[e];
    float4 a = *(const float4*)(h + (size_t)r * 64 + l16 * 4);
    float4 b = *(const float4*)(h + (size_t)c * 64 + l16 * 4);
    float dx = a.x - b.x, dy = a.y - b.y, dz = a.z - b.z, dw = a.w - b.w;
    float s = dx * dx + dy * dy + dz * dz + dw * dw;
    for (int off = 1; off < 16; off <<= 1) s += __shfl_xor(s, off);
    if (l16 == 0) outp[e] = (s < 1e4f ? s : 1e4f);
}

__global__ __launch_bounds__(256) void final_k(const float* __restrict__ h, float* __restrict__ out) {
    int i = blockIdx.x * 256 + threadIdx.x;
    out[i] = h[i];
}

extern "C" void kernel_launch(void* const* d_in, const int* in_sizes, int n_in,
                              void* d_out, int out_size, void* d_ws, size_t ws_size,
                              hipStream_t stream) {
    const float* h_seq = (const float*)d_in[0];
    const float* eattr = (const float*)d_in[1];
    const float* W1 = (const float*)d_in[2];
    const float* b1 = (const float*)d_in[3];
    const float* W2 = (const float*)d_in[4];
    const float* b2 = (const float*)d_in[5];
    const float* Wd1 = (const float*)d_in[6];
    const float* bd1 = (const float*)d_in[7];
    const float* lng = (const float*)d_in[8];
    const float* lnb = (const float*)d_in[9];
    const float* Wd2 = (const float*)d_in[10];
    const float* bd2 = (const float*)d_in[11];
    const int* ei = (const int*)d_in[12];
    float* out = (float*)d_out;

    // Workspace: small/critical first, big msg LAST (ws_size guard).
    char* wsp = (char*)d_ws;
    size_t used = 0;
    auto carve = [&](size_t b) {
        void* p = (void*)(wsp + used);
        used += (b + 255) & ~(size_t)255;
        return p;
    };
    int* counts   = (int*)carve((size_t)NN * 4);
    int* offsets  = (int*)carve((size_t)(NN + 1) * 4);
    int* cursor   = (int*)carve((size_t)NN * 4);
    int* eslot    = (int*)carve((size_t)EE * 4);
    ushort* B1P   = (ushort*)carve(10240 * 2);
    ushort* B2P   = (ushort*)carve(4096 * 2);
    ushort* Wd1P  = (ushort*)carve(8192 * 2);
    ushort* Wd2P  = (ushort*)carve(4096 * 2);
    float* b1f    = (float*)carve(256);
    float* b2f    = (float*)carve(256);
    float* bd1f   = (float*)carve(256);
    float* lngf   = (float*)carve(256);
    float* lnbf   = (float*)carve(256);
    float* bd2f   = (float*)carve(256);
    float* h      = (float*)carve((size_t)NN * 64 * 4);
    ushort* hb    = (ushort*)carve((size_t)NN * 64 * 2);
    float* agg    = (float*)carve((size_t)NN * 64 * 4);
    ushort* msg   = (ushort*)carve((size_t)EE * 64 * 2);   // 51.2 MB — only if it fits
    const bool full = (used <= ws_size);   // deterministic -> graph-capture safe

    prep_edge_k<<<40, 256, 0, stream>>>(W1, W2, b1, b2, B1P, B2P, b1f, b2f);
    prep_node_k<<<32, 256, 0, stream>>>(Wd1, Wd2, bd1, lng, lnb, bd2, Wd1P, Wd2P, bd1f, lngf, lnbf, bd2f);

    for (int t = 0; t < 2; t++) {
        const int* rows = ei + (size_t)t * 2 * EE;
        const int* cols = rows + EE;
        const float* eat = eattr + (size_t)t * EE * 16;
        state_k<<<12500, 256, 0, stream>>>(h, hb, h_seq + (size_t)t * NN * 64, t);
        if (full) {
            zero_k<<<196, 256, 0, stream>>>(counts, NN);
            hist_k<<<1563, 256, 0, stream>>>(rows, counts);
            scan_k<<<1, 1024, 0, stream>>>(counts, offsets, cursor, NN);
            fill_k<<<1563, 256, 0, stream>>>(rows, cursor, eslot);
        }
        for (int s = 0; s < 2; s++) {
            if (full) {
                edge_k<0><<<EGRID, 256, 0, stream>>>(hb, eat, rows, cols,
                                                     B1P, B2P, b1f, b2f, msg, agg);
                agg_k<<<12500, 256, 0, stream>>>(msg, offsets, eslot, agg);
            } else {
                zero_f<<<12500, 256, 0, stream>>>(agg);
                edge_k<1><<<EGRID, 256, 0, stream>>>(hb, eat, rows, cols,
                                                     B1P, B2P, b1f, b2f, msg, agg);
            }
            node_k<<<NBLK, 256, 0, stream>>>(h, hb, agg, Wd1P, Wd2P,
                                             bd1f, lngf, lnbf, bd2f);
        }
        dis_k<<<25000, 256, 0, stream>>>(h, rows, cols, out + (size_t)NN * 64 + (size_t)t * EE);
    }
    final_k<<<12500, 256, 0, stream>>>(h, out);
}

// Round 10
// 979.592 us; speedup vs baseline: 1.6780x; 1.1545x over previous
//
#include <hip/hip_runtime.h>

#define NN 50000
#define EE 400000
#define DD 64
#define NT64 ((EE + 63) / 64)        // 6250 tiles of 64 edges
#define EGRID 768                    // 3 blocks/CU x 256 CUs, one scheduling wave
#define NBLK ((NN + 63) / 64)        // 782 node blocks

typedef __bf16 bf16x8 __attribute__((ext_vector_type(8)));
typedef float f32x4 __attribute__((ext_vector_type(4)));

static __device__ __forceinline__ ushort f2bf(float f) {
    union { float f; unsigned int i; } x; x.f = f;
    unsigned int r = x.i + 0x7fffu + ((x.i >> 16) & 1u);
    return (ushort)(r >> 16);
}
static __device__ __forceinline__ float bf2f(ushort u) {
    union { unsigned int i; float f; } x; x.i = ((unsigned int)u) << 16; return x.f;
}
static __device__ __forceinline__ unsigned pack2(float lo, float hi) {
    return (unsigned)f2bf(lo) | ((unsigned)f2bf(hi) << 16);
}
static __device__ __forceinline__ float fast_tanh(float x) {
    float e = __expf(2.f * x);
    return 1.f - 2.f / (e + 1.f);
}

// ---------------- prep: swizzle f32 weights into bf16 MFMA B-fragment order ----------------
__global__ __launch_bounds__(256) void prep_edge_k(
    const float* __restrict__ W1, const float* __restrict__ W2,
    const float* __restrict__ b1, const float* __restrict__ b2,
    ushort* __restrict__ B1P, ushort* __restrict__ B2P,
    float* __restrict__ b1f, float* __restrict__ b2f)
{
    int idx = blockIdx.x * 256 + threadIdx.x;
    if (idx < 10240) {
        int j = idx & 7, n = (idx >> 3) & 63, qk = idx >> 9;
        int kc = qk >> 2, quad = qk & 3;
        int k = kc * 32 + quad * 8 + j;
        B1P[idx] = (k < 144) ? f2bf(W1[k * 64 + n]) : (ushort)0;
    }
    if (idx < 4096) {
        int j = idx & 7, n = (idx >> 3) & 63, qk = idx >> 9;
        int kc = qk >> 2, quad = qk & 3;
        int k = kc * 32 + quad * 8 + j;
        B2P[idx] = f2bf(W2[k * 64 + n]);
    }
    if (idx < 64) { b1f[idx] = b1[idx]; b2f[idx] = b2[idx]; }
}

__global__ __launch_bounds__(256) void prep_node_k(
    const float* __restrict__ Wd1, const float* __restrict__ Wd2,
    const float* __restrict__ bd1, const float* __restrict__ lng,
    const float* __restrict__ lnb, const float* __restrict__ bd2,
    ushort* __restrict__ Wd1P, ushort* __restrict__ Wd2P,
    float* __restrict__ bd1f, float* __restrict__ lngf,
    float* __restrict__ lnbf, float* __restrict__ bd2f)
{
    int idx = blockIdx.x * 256 + threadIdx.x;
    if (idx < 8192) {
        int j = idx & 7, n = (idx >> 3) & 63, qk = idx >> 9;
        int kc = qk >> 2, quad = qk & 3;
        int k = kc * 32 + quad * 8 + j;
        Wd1P[idx] = f2bf(Wd1[k * 64 + n]);
    }
    if (idx < 4096) {
        int j = idx & 7, n = (idx >> 3) & 63, qk = idx >> 9;
        int kc = qk >> 2, quad = qk & 3;
        int k = kc * 32 + quad * 8 + j;
        Wd2P[idx] = f2bf(Wd2[k * 64 + n]);
    }
    if (idx < 64) {
        bd1f[idx] = bd1[idx]; lngf[idx] = lng[idx];
        lnbf[idx] = lnb[idx]; bd2f[idx] = bd2[idx];
    }
}

// ---------------- state: h = (t==0 ? 2*hseq : h + hseq); bf16 mirror ----------------
__global__ __launch_bounds__(256) void state_k(
    float* __restrict__ h, ushort* __restrict__ hb,
    const float* __restrict__ hseq_t, int mode)
{
    int i = blockIdx.x * 256 + threadIdx.x;
    float v = hseq_t[i];
    float r = (mode == 0) ? (2.f * v) : (h[i] + v);
    h[i] = r; hb[i] = f2bf(r);
}

// ---------------- CSR build ----------------
__global__ __launch_bounds__(256) void zero_k(int* __restrict__ p, int n) {
    int i = blockIdx.x * 256 + threadIdx.x;
    if (i < n) p[i] = 0;
}
__global__ __launch_bounds__(256) void zero_f(float* __restrict__ p) {
    int i = blockIdx.x * 256 + threadIdx.x;
    p[i] = 0.f;
}
__global__ __launch_bounds__(256) void hist_k(const int* __restrict__ rows, int* __restrict__ counts) {
    int e = blockIdx.x * 256 + threadIdx.x;
    if (e < EE) atomicAdd(&counts[rows[e]], 1);
}
__global__ __launch_bounds__(1024) void scan_k(
    const int* __restrict__ counts, int* __restrict__ offsets, int* __restrict__ cursor, int n)
{
    __shared__ int wsum[16];
    __shared__ int carry_s;
    int tid = threadIdx.x, lane = tid & 63, w = tid >> 6;
    if (tid == 0) carry_s = 0;
    __syncthreads();
    for (int base = 0; base < n; base += 1024) {
        int i = base + tid;
        int v = (i < n) ? counts[i] : 0;
        int x = v;
        for (int off = 1; off < 64; off <<= 1) {
            int y = __shfl_up(x, off);
            if (lane >= off) x += y;
        }
        if (lane == 63) wsum[w] = x;
        __syncthreads();
        if (w == 0 && lane < 16) {
            int s = wsum[lane];
            for (int off = 1; off < 16; off <<= 1) {
                int y = __shfl_up(s, off);
                if (lane >= off) s += y;
            }
            wsum[lane] = s;
        }
        __syncthreads();
        int wpre = (w == 0) ? 0 : wsum[w - 1];
        int excl = carry_s + wpre + x - v;
        if (i < n) { offsets[i] = excl; cursor[i] = excl; }
        int total = wsum[15];
        __syncthreads();
        if (tid == 0) carry_s += total;
        __syncthreads();
    }
    if (tid == 0) offsets[n] = carry_s;
}
__global__ __launch_bounds__(256) void fill_k(
    const int* __restrict__ rows, int* __restrict__ cursor, int* __restrict__ eslot)
{
    int e = blockIdx.x * 256 + threadIdx.x;
    if (e < EE) {
        int p = atomicAdd(&cursor[rows[e]], 1);
        if ((unsigned)p < (unsigned)EE) eslot[p] = e;
    }
}

// ---------------- edge MLP: R7-proven block-tile dataflow, 2 barriers/tile ----------------
// LDS: sB1 20480 + sA 21504 + sH 9216 = 51200 B -> 3 blocks/CU.
// B2 fragments live in registers (identical values to the old sB2 copy).
// Barrier A (post-gather): sA RAW; also drains prior tile's layer-2 sH reads.
// Barrier B (post-hidden): sH RAW; also drains layer-1 sA reads -> next gather WAR-safe.
template<int ATOMIC>
__global__ __launch_bounds__(256, 3) void edge_k(
    const ushort* __restrict__ hb, const float* __restrict__ ea,
    const int* __restrict__ rows, const int* __restrict__ cols,
    const ushort* __restrict__ B1P, const ushort* __restrict__ B2P,
    const float* __restrict__ b1f, const float* __restrict__ b2f,
    ushort* __restrict__ msg, float* __restrict__ agg)
{
    __shared__ __attribute__((aligned(16))) ushort sB1[10240];
    __shared__ __attribute__((aligned(16))) ushort sA[64 * 168];  // pad 160->168
    __shared__ __attribute__((aligned(16))) ushort sH[64 * 72];   // pad 64->72

    int tid = threadIdx.x;
    int lane = tid & 63, wave = tid >> 6;
    int m = lane & 15, quad = lane >> 4;

    for (int i = tid; i < 10240 / 8; i += 256) ((uint4*)sB1)[i] = ((const uint4*)B1P)[i];
    // B2 fragments + biases in registers, once per block
    bf16x8 b2r[2][4];
    for (int kc = 0; kc < 2; kc++)
        for (int nt = 0; nt < 4; nt++)
            b2r[kc][nt] = *(const bf16x8*)(B2P + ((kc * 4 + quad) * 64 + nt * 16 + m) * 8);
    float b1v[4], b2v[4];
    for (int nt = 0; nt < 4; nt++) { b1v[nt] = b1f[nt * 16 + m]; b2v[nt] = b2f[nt * 16 + m]; }
    __syncthreads();   // weights staged

    for (int tile = blockIdx.x; tile < NT64; tile += EGRID) {
        int ebase = tile * 64;

        // gather: 64 edges x 20 chunks(16B): [h_row(8)|h_col(8)|ea f32->bf16(2)|zero(2)]
        for (int c = tid; c < 1280; c += 256) {
            int el = c / 20;
            int p = c - el * 20;
            uint4 v;
            if (p < 8) {
                int r = rows[ebase + el];
                v = *(const uint4*)(hb + (size_t)r * 64 + p * 8);
            } else if (p < 16) {
                int cc = cols[ebase + el];
                v = *(const uint4*)(hb + (size_t)cc * 64 + (p - 8) * 8);
            } else if (p < 18) {
                const float* s = ea + (size_t)(ebase + el) * 16 + (p - 16) * 8;
                float4 f0 = ((const float4*)s)[0], f1 = ((const float4*)s)[1];
                v = make_uint4(pack2(f0.x, f0.y), pack2(f0.z, f0.w),
                               pack2(f1.x, f1.y), pack2(f1.z, f1.w));
            } else {
                v = make_uint4(0u, 0u, 0u, 0u);
            }
            *(uint4*)(sA + el * 168 + p * 8) = v;
        }
        __syncthreads();   // barrier A

        // layer 1: [16 edges x 160] @ [160 x 64]
        f32x4 acc[4];
        for (int nt = 0; nt < 4; nt++) acc[nt] = (f32x4){0.f, 0.f, 0.f, 0.f};
        for (int kc = 0; kc < 5; kc++) {
            bf16x8 a = *(const bf16x8*)(sA + (wave * 16 + m) * 168 + kc * 32 + quad * 8);
            for (int nt = 0; nt < 4; nt++) {
                bf16x8 b = *(const bf16x8*)(sB1 + ((kc * 4 + quad) * 64 + nt * 16 + m) * 8);
                acc[nt] = __builtin_amdgcn_mfma_f32_16x16x32_bf16(a, b, acc[nt], 0, 0, 0);
            }
        }
        for (int nt = 0; nt < 4; nt++) {
            int colid = nt * 16 + m;
            float bb = b1v[nt];
            for (int r = 0; r < 4; r++) {
                float v = acc[nt][r] + bb;
                v = v > 0.f ? v : 0.f;
                sH[(wave * 16 + quad * 4 + r) * 72 + colid] = f2bf(v);
            }
        }
        __syncthreads();   // barrier B

        // layer 2: [16 x 64] @ [64 x 64], B from registers
        f32x4 acc2[4];
        for (int nt = 0; nt < 4; nt++) acc2[nt] = (f32x4){0.f, 0.f, 0.f, 0.f};
        for (int kc = 0; kc < 2; kc++) {
            bf16x8 a = *(const bf16x8*)(sH + (wave * 16 + m) * 72 + kc * 32 + quad * 8);
            for (int nt = 0; nt < 4; nt++) {
                acc2[nt] = __builtin_amdgcn_mfma_f32_16x16x32_bf16(a, b2r[kc][nt], acc2[nt], 0, 0, 0);
            }
        }
        for (int nt = 0; nt < 4; nt++) {
            int colid = nt * 16 + m;
            float bb = b2v[nt];
            for (int r = 0; r < 4; r++) {
                float v = acc2[nt][r] + bb;
                int el = wave * 16 + quad * 4 + r;
                if (ATOMIC) {
                    atomicAdd(&agg[(size_t)rows[ebase + el] * 64 + colid], v);
                } else {
                    msg[(size_t)(ebase + el) * 64 + colid] = f2bf(v);
                }
            }
        }
    }
}

// ---------------- aggregate (CSR path): one wave per node, lane = feature ----------------
__global__ __launch_bounds__(256) void agg_k(
    const ushort* __restrict__ msg, const int* __restrict__ offsets,
    const int* __restrict__ eslot, float* __restrict__ agg)
{
    int gw = (blockIdx.x * 256 + threadIdx.x) >> 6;
    int lane = threadIdx.x & 63;
    int beg = offsets[gw], end = offsets[gw + 1];
    beg = beg < 0 ? 0 : beg;
    end = end > EE ? EE : end;
    float a = 0.f;
    for (int i = beg; i < end; i++) {
        int e = eslot[i];
        if ((unsigned)e < (unsigned)EE)
            a += bf2f(msg[(size_t)e * 64 + lane]);
    }
    agg[(size_t)gw * 64 + lane] = a;
}

// ---------------- node MLP (MFMA) + in-register LN + SiLU + tanh + Euler ----------------
__global__ __launch_bounds__(256) void node_k(
    float* __restrict__ h, ushort* __restrict__ hbm,
    const float* __restrict__ agg,
    const ushort* __restrict__ Wd1P, const ushort* __restrict__ Wd2P,
    const float* __restrict__ bd1f, const float* __restrict__ lngf,
    const float* __restrict__ lnbf, const float* __restrict__ bd2f)
{
    __shared__ __attribute__((aligned(16))) ushort sB1[8192];
    __shared__ __attribute__((aligned(16))) ushort sB2[4096];
    __shared__ __attribute__((aligned(16))) ushort sA[64 * 136];
    __shared__ __attribute__((aligned(16))) ushort sX[64 * 72];
    int tid = threadIdx.x;
    int lane = tid & 63, wave = tid >> 6;
    int m = lane & 15, quad = lane >> 4;
    int nbase = blockIdx.x * 64;

    for (int i = tid; i < 8192 / 8; i += 256) ((uint4*)sB1)[i] = ((const uint4*)Wd1P)[i];
    for (int i = tid; i < 4096 / 8; i += 256) ((uint4*)sB2)[i] = ((const uint4*)Wd2P)[i];

    for (int c = tid; c < 1024; c += 256) {
        int nd = c >> 4, p = c & 15;
        int n = nbase + nd; n = n < NN ? n : NN - 1;   // clamped rows are compute-only
        const float* src = (p < 8) ? (h + (size_t)n * 64 + p * 8)
                                   : (agg + (size_t)n * 64 + (p - 8) * 8);
        float4 f0 = ((const float4*)src)[0], f1 = ((const float4*)src)[1];
        *(uint4*)(sA + nd * 136 + p * 8) =
            make_uint4(pack2(f0.x, f0.y), pack2(f0.z, f0.w),
                       pack2(f1.x, f1.y), pack2(f1.z, f1.w));
    }
    __syncthreads();

    f32x4 acc[4];
    for (int nt = 0; nt < 4; nt++) acc[nt] = (f32x4){0.f, 0.f, 0.f, 0.f};
    for (int kc = 0; kc < 4; kc++) {
        bf16x8 a = *(const bf16x8*)(sA + (wave * 16 + m) * 136 + kc * 32 + quad * 8);
        for (int nt = 0; nt < 4; nt++) {
            bf16x8 b = *(const bf16x8*)(sB1 + ((kc * 4 + quad) * 64 + nt * 16 + m) * 8);
            acc[nt] = __builtin_amdgcn_mfma_f32_16x16x32_bf16(a, b, acc[nt], 0, 0, 0);
        }
    }

    float gA[4], bA[4], d1[4], d2[4];
    for (int nt = 0; nt < 4; nt++) {
        int f = nt * 16 + m;
        d1[nt] = bd1f[f]; gA[nt] = lngf[f]; bA[nt] = lnbf[f]; d2[nt] = bd2f[f];
    }
    float xs[4][4];
    for (int nt = 0; nt < 4; nt++)
        for (int r = 0; r < 4; r++)
            xs[nt][r] = acc[nt][r] + d1[nt];

    for (int r = 0; r < 4; r++) {
        float s1 = 0.f, s2 = 0.f;
        for (int nt = 0; nt < 4; nt++) { float v = xs[nt][r]; s1 += v; s2 += v * v; }
        for (int off = 1; off < 16; off <<= 1) {
            s1 += __shfl_xor(s1, off);
            s2 += __shfl_xor(s2, off);
        }
        float mean = s1 * (1.f / 64.f);
        float var = fmaxf(s2 * (1.f / 64.f) - mean * mean, 0.f);
        float rstd = rsqrtf(var + 1e-5f);
        int nrow = wave * 16 + quad * 4 + r;
        for (int nt = 0; nt < 4; nt++) {
            float xn = (xs[nt][r] - mean) * rstd * gA[nt] + bA[nt];
            float sl = xn / (1.f + __expf(-xn));
            sX[nrow * 72 + nt * 16 + m] = f2bf(sl);
        }
    }
    __syncthreads();

    f32x4 acc2[4];
    for (int nt = 0; nt < 4; nt++) acc2[nt] = (f32x4){0.f, 0.f, 0.f, 0.f};
    for (int kc = 0; kc < 2; kc++) {
        bf16x8 a = *(const bf16x8*)(sX + (wave * 16 + m) * 72 + kc * 32 + quad * 8);
        for (int nt = 0; nt < 4; nt++) {
            bf16x8 b = *(const bf16x8*)(sB2 + ((kc * 4 + quad) * 64 + nt * 16 + m) * 8);
            acc2[nt] = __builtin_amdgcn_mfma_f32_16x16x32_bf16(a, b, acc2[nt], 0, 0, 0);
        }
    }

    // RMW h: ONLY in-range slots write (tail duplicates racing the RMW was the R6 bug)
    for (int r = 0; r < 4; r++) {
        int g = nbase + wave * 16 + quad * 4 + r;
        if (g < NN) {
            for (int nt = 0; nt < 4; nt++) {
                int f = nt * 16 + m;
                float y = fast_tanh(acc2[nt][r] + d2[nt]);
                float hn = h[(size_t)g * 64 + f] + 0.5f * y;
                h[(size_t)g * 64 + f] = hn;
                hbm[(size_t)g * 64 + f] = f2bf(hn);
            }
        }
    }
}

// ---------------- disagreement (f32) + final (f32) ----------------
__global__ __launch_bounds__(256) void dis_k(
    const float* __restrict__ h, const int* __restrict__ rows,
    const int* __restrict__ cols, float* __restrict__ outp)
{
    int tid = threadIdx.x;
    int e = blockIdx.x * 16 + (tid >> 4);
    int l16 = tid & 15;
    int r = rows[e], c = cols[e];
    float4 a = *(const float4*)(h + (size_t)r * 64 + l16 * 4);
    float4 b = *(const float4*)(h + (size_t)c * 64 + l16 * 4);
    float dx = a.x - b.x, dy = a.y - b.y, dz = a.z - b.z, dw = a.w - b.w;
    float s = dx * dx + dy * dy + dz * dz + dw * dw;
    for (int off = 1; off < 16; off <<= 1) s += __shfl_xor(s, off);
    if (l16 == 0) outp[e] = (s < 1e4f ? s : 1e4f);
}

__global__ __launch_bounds__(256) void final_k(const float* __restrict__ h, float* __restrict__ out) {
    int i = blockIdx.x * 256 + threadIdx.x;
    out[i] = h[i];
}

extern "C" void kernel_launch(void* const* d_in, const int* in_sizes, int n_in,
                              void* d_out, int out_size, void* d_ws, size_t ws_size,
                              hipStream_t stream) {
    const float* h_seq = (const float*)d_in[0];
    const float* eattr = (const float*)d_in[1];
    const float* W1 = (const float*)d_in[2];
    const float* b1 = (const float*)d_in[3];
    const float* W2 = (const float*)d_in[4];
    const float* b2 = (const float*)d_in[5];
    const float* Wd1 = (const float*)d_in[6];
    const float* bd1 = (const float*)d_in[7];
    const float* lng = (const float*)d_in[8];
    const float* lnb = (const float*)d_in[9];
    const float* Wd2 = (const float*)d_in[10];
    const float* bd2 = (const float*)d_in[11];
    const int* ei = (const int*)d_in[12];
    float* out = (float*)d_out;

    char* wsp = (char*)d_ws;
    size_t used = 0;
    auto carve = [&](size_t b) {
        void* p = (void*)(wsp + used);
        used += (b + 255) & ~(size_t)255;
        return p;
    };
    int* counts   = (int*)carve((size_t)NN * 4);
    int* offsets  = (int*)carve((size_t)(NN + 1) * 4);
    int* cursor   = (int*)carve((size_t)NN * 4);
    int* eslot    = (int*)carve((size_t)EE * 4);
    ushort* B1P   = (ushort*)carve(10240 * 2);
    ushort* B2P   = (ushort*)carve(4096 * 2);
    ushort* Wd1P  = (ushort*)carve(8192 * 2);
    ushort* Wd2P  = (ushort*)carve(4096 * 2);
    float* b1f    = (float*)carve(256);
    float* b2f    = (float*)carve(256);
    float* bd1f   = (float*)carve(256);
    float* lngf   = (float*)carve(256);
    float* lnbf   = (float*)carve(256);
    float* bd2f   = (float*)carve(256);
    float* h      = (float*)carve((size_t)NN * 64 * 4);
    ushort* hb    = (ushort*)carve((size_t)NN * 64 * 2);
    float* agg    = (float*)carve((size_t)NN * 64 * 4);
    ushort* msg   = (ushort*)carve((size_t)EE * 64 * 2);
    const bool full = (used <= ws_size);

    prep_edge_k<<<40, 256, 0, stream>>>(W1, W2, b1, b2, B1P, B2P, b1f, b2f);
    prep_node_k<<<32, 256, 0, stream>>>(Wd1, Wd2, bd1, lng, lnb, bd2, Wd1P, Wd2P, bd1f, lngf, lnbf, bd2f);

    for (int t = 0; t < 2; t++) {
        const int* rows = ei + (size_t)t * 2 * EE;
        const int* cols = rows + EE;
        const float* eat = eattr + (size_t)t * EE * 16;
        state_k<<<12500, 256, 0, stream>>>(h, hb, h_seq + (size_t)t * NN * 64, t);
        if (full) {
            zero_k<<<196, 256, 0, stream>>>(counts, NN);
            hist_k<<<1563, 256, 0, stream>>>(rows, counts);
            scan_k<<<1, 1024, 0, stream>>>(counts, offsets, cursor, NN);
            fill_k<<<1563, 256, 0, stream>>>(rows, cursor, eslot);
        }
        for (int s = 0; s < 2; s++) {
            if (full) {
                edge_k<0><<<EGRID, 256, 0, stream>>>(hb, eat, rows, cols,
                                                     B1P, B2P, b1f, b2f, msg, agg);
                agg_k<<<12500, 256, 0, stream>>>(msg, offsets, eslot, agg);
            } else {
                zero_f<<<12500, 256, 0, stream>>>(agg);
                edge_k<1><<<EGRID, 256, 0, stream>>>(hb, eat, rows, cols,
                                                     B1P, B2P, b1f, b2f, msg, agg);
            }
            node_k<<<NBLK, 256, 0, stream>>>(h, hb, agg, Wd1P, Wd2P,
                                             bd1f, lngf, lnbf, bd2f);
        }
        dis_k<<<25000, 256, 0, stream>>>(h, rows, cols, out + (size_t)NN * 64 + (size_t)t * EE);
    }
    final_k<<<12500, 256, 0, stream>>>(h, out);
}